// Round 3
// baseline (346.493 us; speedup 1.0000x reference)
//
#include <hip/hip_runtime.h>

// Problem constants (from reference)
#define BQ 2
#define HQ 16
#define SQ 8192
#define DQ 128
#define LW 32        // window length
#define STR 16       // stride
#define NWIN 511     // (8192-32)/16 + 1
#define NBLK 512     // NWIN + 1 zero block
#define WPB 4        // windows per workgroup
#define NWG_PER_HEAD 128  // ceil(511/4)

typedef float f32x4 __attribute__((ext_vector_type(4)));
typedef short s16x8 __attribute__((ext_vector_type(8)));

// LDS region map (32 KB total, regions reused as the pyramid shrinks):
//   chunk0 @0     (8K)  window buffer (double-buffered)
//   chunk1 @8192  (8K)
//   s0out  @16384 (16K: 64 rows x 256B)
//   s1out  @0     (8K: 32 rows)   -- chunk0 dead by then
//   s2out  @8192  (4K: 16 rows)   -- chunk1 dead by then
//   s3out  @12288 (2K: 8 rows)
//   s4out  @14336 (1K: 4 rows)
#define R_S0 16384u
#define R_S1 0u
#define R_S2 8192u
#define R_S3 12288u
#define R_S4 14336u

// XOR swizzle keyed on 512B granule: spreads stride-512B A-row reads across
// banks (G4/T2). Involution on global LDS byte offsets; writer+reader agree.
static __device__ __forceinline__ unsigned swz(unsigned b) {
    return b ^ (((b >> 9) & 7u) << 4);
}

static __device__ __forceinline__ short f2bf(float f) {
    __bf16 h = (__bf16)f;
    return __builtin_bit_cast(short, h);
}

static __device__ __forceinline__ float silu(float v) {
    return v / (1.f + __expf(-v));
}

// ---- pass 0: convert weights f32 -> bf16 into workspace ----
// ws layout: wd_bf[5][128][256] (163840 shorts) then wstop_bf[128][128] (16384)
__global__ void convw_kernel(const float* __restrict__ wd,
                             const float* __restrict__ wstop,
                             short* __restrict__ o) {
    int i = blockIdx.x * 256 + threadIdx.x;
    if (i < 163840) {
        o[i] = f2bf(wd[i]);
    } else if (i < 180224) {
        o[i] = f2bf(wstop[i - 163840]);
    }
}

// ---- pass 1: zero the prepended zero-block outputs (silu chain of 0 -> 0) ----
__global__ void zero_kernel(float* __restrict__ out) {
    int i = blockIdx.x * 256 + threadIdx.x;  // 4096 = 32 heads * 128
    int bh = i >> 7, d = i & 127;
    out[(size_t)bh * NBLK * DQ + d] = 0.f;
}

// ---- pass 2: fused compressor ----
// grid: 32 heads * 128 window-groups = 4096 blocks, 512 threads (8 waves).
// LDS 32KB + VGPR<=64 -> 4 blocks/CU = 32 waves/CU (100% occupancy).
// Wave w owns n-tile w for all stages. Window chunks double-buffered and
// overlapped with stage-0 MFMA (issue loads early, ds_write late).
__global__ __launch_bounds__(512, 8)
void fused_kernel(const float* __restrict__ kin,
                  const float* __restrict__ pe,
                  const short* __restrict__ wdb,   // bf16 weights in ws
                  float* __restrict__ out) {
    __shared__ __align__(16) unsigned char lds[32768];
    const short* wsb = wdb + 163840;

    const int bh = blockIdx.x >> 7;           // 0..31
    const int w0 = (blockIdx.x & 127) * WPB;  // first window of this group
    const int tid  = threadIdx.x;
    const int lane = tid & 63;
    const int nt   = tid >> 6;               // wave index == n-tile 0..7
    const int kl   = lane >> 4;              // 0..3
    const int nl   = lane & 15;              // 0..15

    const float* kb = kin + (size_t)bh * SQ * DQ;

    // phase-A task for this thread: one 16B chunk of one window row
    const int arow = tid >> 4;                // 0..31 (row within window)
    const int ac8  = tid & 15;                // 0..15 (8-float chunk)
    const float* pp = pe + arow * DQ + ac8 * 8;
    const f32x4 p0 = *(const f32x4*)pp;
    const f32x4 p1 = *(const f32x4*)(pp + 4);

    // load window w into regs
    f32x4 a0, a1;
    {
        int srow = STR * w0 + arow;
        if (srow > SQ - 1) srow = SQ - 1;
        const float* kp = kb + (size_t)srow * DQ + ac8 * 8;
        a0 = *(const f32x4*)kp;
        a1 = *(const f32x4*)(kp + 4);
    }
    // stage-0 B fragments (resident across mm loop)
    s16x8 b0[8];
    #pragma unroll
    for (int kt = 0; kt < 8; ++kt)
        b0[kt] = *(const s16x8*)(wdb + (nt * 16 + nl) * 256 + kt * 32 + kl * 8);

    // write window 0 to chunk0
    {
        s16x8 v;
        v[0] = f2bf(a0[0] + p0[0]); v[1] = f2bf(a0[1] + p0[1]);
        v[2] = f2bf(a0[2] + p0[2]); v[3] = f2bf(a0[3] + p0[3]);
        v[4] = f2bf(a1[0] + p1[0]); v[5] = f2bf(a1[1] + p1[1]);
        v[6] = f2bf(a1[2] + p1[2]); v[7] = f2bf(a1[3] + p1[3]);
        unsigned ob = (unsigned)((arow << 8) + (ac8 << 4));
        *(s16x8*)(lds + swz(ob)) = v;
    }

    // ---- stage 0: 4 m-tiles == 4 windows, double-buffered ----
    for (int mm = 0; mm < 4; ++mm) {
        __syncthreads();   // chunk[mm&1] visible; prev reads of other buf done
        // issue next window's global loads early (latency hides under MFMA)
        if (mm < 3) {
            int srow = STR * (w0 + mm + 1) + arow;
            if (srow > SQ - 1) srow = SQ - 1;
            const float* kp = kb + (size_t)srow * DQ + ac8 * 8;
            a0 = *(const f32x4*)kp;
            a1 = *(const f32x4*)(kp + 4);
        }
        const unsigned cb = (mm & 1) ? 8192u : 0u;
        s16x8 afr[8];
        #pragma unroll
        for (int kt = 0; kt < 8; ++kt) {
            unsigned bb = cb + (unsigned)((nl << 9) + (kt << 6) + (kl << 4));
            afr[kt] = *(const s16x8*)(lds + swz(bb));
        }
        f32x4 acc = {0.f, 0.f, 0.f, 0.f};
        #pragma unroll
        for (int kt = 0; kt < 8; ++kt)
            acc = __builtin_amdgcn_mfma_f32_16x16x32_bf16(afr[kt], b0[kt], acc, 0, 0, 0);
        #pragma unroll
        for (int r4 = 0; r4 < 4; ++r4) {
            float v = silu(acc[r4]);
            int orow = mm * 16 + kl * 4 + r4;   // < 64 always
            unsigned ob = R_S0 + (unsigned)((orow << 8) + ((nt * 16 + nl) << 1));
            *(short*)(lds + swz(ob)) = f2bf(v);
        }
        // late ds_write of next window into the other chunk buffer
        if (mm < 3) {
            s16x8 v;
            v[0] = f2bf(a0[0] + p0[0]); v[1] = f2bf(a0[1] + p0[1]);
            v[2] = f2bf(a0[2] + p0[2]); v[3] = f2bf(a0[3] + p0[3]);
            v[4] = f2bf(a1[0] + p1[0]); v[5] = f2bf(a1[1] + p1[1]);
            v[6] = f2bf(a1[2] + p1[2]); v[7] = f2bf(a1[3] + p1[3]);
            unsigned ob = (cb ^ 8192u) + (unsigned)((arow << 8) + (ac8 << 4));
            *(s16x8*)(lds + swz(ob)) = v;
        }
    }
    __syncthreads();   // s0out complete

    // ---- stages 1..4 ----
    const unsigned rin[4]  = {R_S0, R_S1, R_S2, R_S3};
    const unsigned rout[4] = {R_S1, R_S2, R_S3, R_S4};
    #pragma unroll
    for (int s = 1; s <= 4; ++s) {
        const short* W = wdb + s * 32768;
        s16x8 bfr[8];
        #pragma unroll
        for (int kt = 0; kt < 8; ++kt)
            bfr[kt] = *(const s16x8*)(W + (nt * 16 + nl) * 256 + kt * 32 + kl * 8);

        const unsigned inoff  = rin[s - 1];
        const unsigned outoff = rout[s - 1];
        const int Mout = 64 >> s;            // 32,16,8,4
        const int mt = (s == 1) ? 2 : 1;

        for (int m = 0; m < mt; ++m) {
            int r = m * 16 + nl;
            int rc = (r < Mout) ? r : (Mout - 1);   // clamp dead A-rows in-bounds
            s16x8 afr[8];
            #pragma unroll
            for (int kt = 0; kt < 8; ++kt) {
                unsigned bb = inoff + (unsigned)((rc << 9) + (kt << 6) + (kl << 4));
                afr[kt] = *(const s16x8*)(lds + swz(bb));
            }
            f32x4 acc = {0.f, 0.f, 0.f, 0.f};
            #pragma unroll
            for (int kt = 0; kt < 8; ++kt)
                acc = __builtin_amdgcn_mfma_f32_16x16x32_bf16(afr[kt], bfr[kt], acc, 0, 0, 0);
            #pragma unroll
            for (int r4 = 0; r4 < 4; ++r4) {
                int orow = m * 16 + kl * 4 + r4;
                if (orow < Mout) {
                    float v = silu(acc[r4]);
                    unsigned ob = outoff + (unsigned)((orow << 8) + ((nt * 16 + nl) << 1));
                    *(short*)(lds + swz(ob)) = f2bf(v);
                }
            }
        }
        __syncthreads();
    }

    // ---- w_stop (no activation), input @R_S4 (4 rows x 256B), K=128 ----
    {
        s16x8 bfr[4];
        #pragma unroll
        for (int kt = 0; kt < 4; ++kt)
            bfr[kt] = *(const s16x8*)(wsb + (nt * 16 + nl) * 128 + kt * 32 + kl * 8);
        int rc = (nl < 4) ? nl : 3;
        s16x8 afr[4];
        #pragma unroll
        for (int kt = 0; kt < 4; ++kt) {
            unsigned bb = R_S4 + (unsigned)((rc << 8) + (kt << 6) + (kl << 4));
            afr[kt] = *(const s16x8*)(lds + swz(bb));
        }
        f32x4 acc = {0.f, 0.f, 0.f, 0.f};
        #pragma unroll
        for (int kt = 0; kt < 4; ++kt)
            acc = __builtin_amdgcn_mfma_f32_16x16x32_bf16(afr[kt], bfr[kt], acc, 0, 0, 0);
        if (kl == 0) {
            #pragma unroll
            for (int r4 = 0; r4 < 4; ++r4) {
                int w = w0 + r4;               // C row r4 == window index
                if (w < NWIN) {
                    out[((size_t)bh * NBLK + (w + 1)) * DQ + nt * 16 + nl] = acc[r4];
                }
            }
        }
    }
}

extern "C" void kernel_launch(void* const* d_in, const int* in_sizes, int n_in,
                              void* d_out, int out_size, void* d_ws, size_t ws_size,
                              hipStream_t stream) {
    const float* kin   = (const float*)d_in[0];
    const float* pe    = (const float*)d_in[1];
    const float* wdown = (const float*)d_in[2];
    const float* wstop = (const float*)d_in[3];
    float* out = (float*)d_out;
    short* wbf = (short*)d_ws;   // 180224 shorts = 352.4 KB

    convw_kernel<<<704, 256, 0, stream>>>(wdown, wstop, wbf);
    zero_kernel<<<16, 256, 0, stream>>>(out);
    fused_kernel<<<BQ * HQ * NWG_PER_HEAD, 512, 0, stream>>>(kin, pe, wbf, out);
}

// Round 4
// 128.550 us; speedup vs baseline: 2.6954x; 2.6954x over previous
//
#include <hip/hip_runtime.h>

// Problem constants (from reference)
#define BQ 2
#define HQ 16
#define SQ 8192
#define DQ 128
#define STR 16
#define NWIN 511     // (8192-32)/16 + 1
#define NBLK 512     // NWIN + 1 zero block
#define WPB 8        // windows per workgroup
#define NWG_PER_HEAD 64

typedef float f32x4 __attribute__((ext_vector_type(4)));
typedef short s16x8 __attribute__((ext_vector_type(8)));

// LDS 64 KB map (regions reused as the pyramid shrinks):
//   chunkA @0      16 KB (2 windows x 32 rows x 256B)
//   chunkB @16384  16 KB
//   s0out  @32768  32 KB (128 rows x 256B)
//   s1out  @0      16 KB (64 rows)   -- chunkA dead
//   s2out  @16384   8 KB (32 rows)   -- chunkB dead
//   s3out  @24576   4 KB (16 rows)
//   s4out  @28672   2 KB (8 rows)
#define R_S0 32768u
#define R_S1 0u
#define R_S2 16384u
#define R_S3 24576u
#define R_S4 28672u

// XOR swizzle keyed on 512B granule (G4/T2). Involution on global LDS byte
// offsets; all writers and readers apply it consistently.
static __device__ __forceinline__ unsigned swz(unsigned b) {
    return b ^ (((b >> 9) & 7u) << 4);
}

static __device__ __forceinline__ short f2bf(float f) {
    __bf16 h = (__bf16)f;
    return __builtin_bit_cast(short, h);
}

static __device__ __forceinline__ float silu(float v) {
    return v / (1.f + __expf(-v));
}

// ---- pass 0a: convert weights f32 -> bf16 into workspace ----
// ws layout: wd_bf[5][128][256] (163840 sh) + wstop_bf[128][128] (16384 sh)
//            + bias0 f32[16][128] at byte 360448
__global__ void convw_kernel(const float* __restrict__ wd,
                             const float* __restrict__ wstop,
                             short* __restrict__ o) {
    int i = blockIdx.x * 256 + threadIdx.x;
    if (i < 163840) {
        o[i] = f2bf(wd[i]);
    } else if (i < 180224) {
        o[i] = f2bf(wstop[i - 163840]);
    }
}

// ---- pass 0b: bias0[j][c] = sum_i W0[c][i] * concat(pe[2j],pe[2j+1])[i] ----
__global__ void bias0_kernel(const float* __restrict__ wd,
                             const float* __restrict__ pe,
                             float* __restrict__ bias) {
    int o = blockIdx.x * 256 + threadIdx.x;   // 0..2047
    int j = o >> 7;
    int c = o & 127;
    const float* w  = wd + (size_t)c * 256;
    const float* p0 = pe + (2 * j) * DQ;
    const float* p1 = pe + (2 * j + 1) * DQ;
    float s = 0.f;
    #pragma unroll 4
    for (int i = 0; i < 128; ++i) s += w[i] * p0[i];
    #pragma unroll 4
    for (int i = 0; i < 128; ++i) s += w[i + 128] * p1[i];
    bias[o] = s;
}

// ---- pass 1: zero the prepended zero-block outputs (silu chain of 0 -> 0) ----
__global__ void zero_kernel(float* __restrict__ out) {
    int i = blockIdx.x * 256 + threadIdx.x;  // 4096 = 32 heads * 128
    int bh = i >> 7, d = i & 127;
    out[(size_t)bh * NBLK * DQ + d] = 0.f;
}

// ---- pass 2: fused compressor ----
// grid: 32 heads * 64 groups = 2048 blocks, 512 threads (8 waves).
// 64KB LDS + VGPR<=128 -> 2 blocks/CU = 16 waves/CU, spill-free.
// Wave w owns n-tile w for all stages; pe folded into bias0 (acc init).
__global__ __launch_bounds__(512, 4)
void fused_kernel(const float* __restrict__ kin,
                  const short* __restrict__ wdb,
                  const float* __restrict__ bias0,
                  float* __restrict__ out) {
    __shared__ __align__(16) unsigned char lds[65536];
    const short* wsb = wdb + 163840;

    const int bh = blockIdx.x >> 6;           // 0..31
    const int w0 = (blockIdx.x & 63) * WPB;   // first window of this group
    const int tid  = threadIdx.x;
    const int lane = tid & 63;
    const int nt   = tid >> 6;               // wave index == n-tile 0..7
    const int kl   = lane >> 4;              // 0..3
    const int nl   = lane & 15;              // 0..15

    const float* kb = kin + (size_t)bh * SQ * DQ;

    // phase-A task: rows r (two windows wi=0/1 at same r,c8)
    const int r   = tid >> 4;                 // 0..31
    const int ac8 = tid & 15;                 // 0..15

    // stage-0 bias fragment (acc init), independent of m-tile
    f32x4 bias;
    #pragma unroll
    for (int r4 = 0; r4 < 4; ++r4)
        bias[r4] = bias0[(kl * 4 + r4) * 128 + nt * 16 + nl];

    // stage-0 B fragments (resident across chunk loop)
    s16x8 b0[8];
    #pragma unroll
    for (int kt = 0; kt < 8; ++kt)
        b0[kt] = *(const s16x8*)(wdb + (nt * 16 + nl) * 256 + kt * 32 + kl * 8);

    // load + write chunk 0 (windows w0, w0+1) into chunkA
    {
        #pragma unroll
        for (int wi = 0; wi < 2; ++wi) {
            int srow = STR * (w0 + wi) + r;
            if (srow > SQ - 1) srow = SQ - 1;
            const float* kp = kb + (size_t)srow * DQ + ac8 * 8;
            f32x4 a0 = *(const f32x4*)kp;
            f32x4 a1 = *(const f32x4*)(kp + 4);
            s16x8 v;
            v[0] = f2bf(a0[0]); v[1] = f2bf(a0[1]); v[2] = f2bf(a0[2]); v[3] = f2bf(a0[3]);
            v[4] = f2bf(a1[0]); v[5] = f2bf(a1[1]); v[6] = f2bf(a1[2]); v[7] = f2bf(a1[3]);
            unsigned ob = (unsigned)(((wi * 32 + r) << 8) + (ac8 << 4));
            *(s16x8*)(lds + swz(ob)) = v;
        }
    }

    // ---- stage 0: 4 chunk iterations, double-buffered, loads prefetched ----
    for (int c = 0; c < 4; ++c) {
        __syncthreads();   // chunk[c&1] ready; other buffer's readers done
        const unsigned cb  = (c & 1) ? 16384u : 0u;
        const unsigned cbn = cb ^ 16384u;

        // prefetch next chunk's global data (consumed after MFMAs)
        f32x4 n00, n01, n10, n11;
        if (c < 3) {
            #pragma unroll
            for (int wi = 0; wi < 2; ++wi) {
                int srow = STR * (w0 + (c + 1) * 2 + wi) + r;
                if (srow > SQ - 1) srow = SQ - 1;
                const float* kp = kb + (size_t)srow * DQ + ac8 * 8;
                if (wi == 0) { n00 = *(const f32x4*)kp; n01 = *(const f32x4*)(kp + 4); }
                else         { n10 = *(const f32x4*)kp; n11 = *(const f32x4*)(kp + 4); }
            }
        }

        // two m-tiles (= two windows) of stage 0
        #pragma unroll
        for (int mm = 0; mm < 2; ++mm) {
            s16x8 afr[8];
            #pragma unroll
            for (int kt = 0; kt < 8; ++kt) {
                unsigned bb = cb + (unsigned)(((mm * 16 + nl) << 9) + (kt << 6) + (kl << 4));
                afr[kt] = *(const s16x8*)(lds + swz(bb));
            }
            f32x4 acc = bias;
            #pragma unroll
            for (int kt = 0; kt < 8; ++kt)
                acc = __builtin_amdgcn_mfma_f32_16x16x32_bf16(afr[kt], b0[kt], acc, 0, 0, 0);
            #pragma unroll
            for (int r4 = 0; r4 < 4; ++r4) {
                float v = silu(acc[r4]);
                int orow = (c * 2 + mm) * 16 + kl * 4 + r4;   // 0..127
                unsigned ob = R_S0 + (unsigned)((orow << 8) + ((nt * 16 + nl) << 1));
                *(short*)(lds + swz(ob)) = f2bf(v);
            }
        }

        // late convert+write of prefetched chunk into the other buffer
        if (c < 3) {
            s16x8 v;
            v[0] = f2bf(n00[0]); v[1] = f2bf(n00[1]); v[2] = f2bf(n00[2]); v[3] = f2bf(n00[3]);
            v[4] = f2bf(n01[0]); v[5] = f2bf(n01[1]); v[6] = f2bf(n01[2]); v[7] = f2bf(n01[3]);
            unsigned ob = cbn + (unsigned)((r << 8) + (ac8 << 4));
            *(s16x8*)(lds + swz(ob)) = v;
            v[0] = f2bf(n10[0]); v[1] = f2bf(n10[1]); v[2] = f2bf(n10[2]); v[3] = f2bf(n10[3]);
            v[4] = f2bf(n11[0]); v[5] = f2bf(n11[1]); v[6] = f2bf(n11[2]); v[7] = f2bf(n11[3]);
            ob = cbn + (unsigned)(((32 + r) << 8) + (ac8 << 4));
            *(s16x8*)(lds + swz(ob)) = v;
        }
    }
    __syncthreads();   // s0out complete

    // ---- stages 1..4 (input rows 128,64,32,16 of 256B; A-rows = half) ----
    const unsigned rin[4]  = {R_S0, R_S1, R_S2, R_S3};
    const unsigned rout[4] = {R_S1, R_S2, R_S3, R_S4};
    #pragma unroll
    for (int s = 1; s <= 4; ++s) {
        const short* W = wdb + s * 32768;
        s16x8 bfr[8];
        #pragma unroll
        for (int kt = 0; kt < 8; ++kt)
            bfr[kt] = *(const s16x8*)(W + (nt * 16 + nl) * 256 + kt * 32 + kl * 8);

        const unsigned inoff  = rin[s - 1];
        const unsigned outoff = rout[s - 1];
        const int Arows = 64 >> (s - 1);     // 64,32,16,8  (also = Mout)
        const int mt = (Arows + 15) >> 4;    // 4,2,1,1

        for (int m = 0; m < mt; ++m) {
            int ar = m * 16 + nl;
            if (ar > Arows - 1) ar = Arows - 1;   // clamp dead A-rows (stage 4)
            s16x8 afr[8];
            #pragma unroll
            for (int kt = 0; kt < 8; ++kt) {
                unsigned bb = inoff + (unsigned)((ar << 9) + (kt << 6) + (kl << 4));
                afr[kt] = *(const s16x8*)(lds + swz(bb));
            }
            f32x4 acc = {0.f, 0.f, 0.f, 0.f};
            #pragma unroll
            for (int kt = 0; kt < 8; ++kt)
                acc = __builtin_amdgcn_mfma_f32_16x16x32_bf16(afr[kt], bfr[kt], acc, 0, 0, 0);
            #pragma unroll
            for (int r4 = 0; r4 < 4; ++r4) {
                int orow = m * 16 + kl * 4 + r4;
                if (orow < Arows) {
                    float v = silu(acc[r4]);
                    unsigned ob = outoff + (unsigned)((orow << 8) + ((nt * 16 + nl) << 1));
                    *(short*)(lds + swz(ob)) = f2bf(v);
                }
            }
        }
        __syncthreads();
    }

    // ---- w_stop (no activation): 8 rows x 128, K=128, write f32 out ----
    {
        s16x8 bfr[4];
        #pragma unroll
        for (int kt = 0; kt < 4; ++kt)
            bfr[kt] = *(const s16x8*)(wsb + (nt * 16 + nl) * 128 + kt * 32 + kl * 8);
        int ar = (nl < 8) ? nl : 7;
        s16x8 afr[4];
        #pragma unroll
        for (int kt = 0; kt < 4; ++kt) {
            unsigned bb = R_S4 + (unsigned)((ar << 8) + (kt << 6) + (kl << 4));
            afr[kt] = *(const s16x8*)(lds + swz(bb));
        }
        f32x4 acc = {0.f, 0.f, 0.f, 0.f};
        #pragma unroll
        for (int kt = 0; kt < 4; ++kt)
            acc = __builtin_amdgcn_mfma_f32_16x16x32_bf16(afr[kt], bfr[kt], acc, 0, 0, 0);
        if (kl < 2) {
            #pragma unroll
            for (int r4 = 0; r4 < 4; ++r4) {
                int w = w0 + kl * 4 + r4;      // C row = window index (0..7 valid)
                if (w < NWIN) {
                    out[((size_t)bh * NBLK + (w + 1)) * DQ + nt * 16 + nl] = acc[r4];
                }
            }
        }
    }
}

extern "C" void kernel_launch(void* const* d_in, const int* in_sizes, int n_in,
                              void* d_out, int out_size, void* d_ws, size_t ws_size,
                              hipStream_t stream) {
    const float* kin   = (const float*)d_in[0];
    const float* pe    = (const float*)d_in[1];
    const float* wdown = (const float*)d_in[2];
    const float* wstop = (const float*)d_in[3];
    float* out = (float*)d_out;
    short* wbf  = (short*)d_ws;                       // 180224 shorts
    float* bias = (float*)((char*)d_ws + 360448);     // f32[2048]

    convw_kernel<<<704, 256, 0, stream>>>(wdown, wstop, wbf);
    bias0_kernel<<<8, 256, 0, stream>>>(wdown, pe, bias);
    zero_kernel<<<16, 256, 0, stream>>>(out);
    fused_kernel<<<BQ * HQ * NWG_PER_HEAD, 512, 0, stream>>>(kin, wbf, bias, out);
}